// Round 2
// baseline (2420.154 us; speedup 1.0000x reference)
//
#include <hip/hip_runtime.h>
#include <math.h>

// Problem constants (from setup_inputs): B=4, Cin=32, Cout=64
// x: (4,32,256,256)  prev_h/prev_c: (4,64,320,320)
// Wc: (64,32,5,5) bc: (64)  Wg: (256,128,3,3) bg: (256)
// ey=64 ex=64 eh=256 ew=256 -> ey2=ex2=32, eh2=ew2=128, pad=1
// x_conv: (4,64,128,128); stacked: (4,128,130,130); gates: (4,256,128,128)
// out layout: hidden (4,64,128,128) | new_h (4,64,320,320) | new_c (4,64,320,320)

#define OFF_NEWH 4194304
#define OFF_NEWC 30408704

__device__ __forceinline__ float sigm(float v) { return 1.0f / (1.0f + expf(-v)); }

// ---------------------------------------------------------------------------
// conv1: x (4,32,256,256) -> xconv (4,64,128,128), 5x5 stride2 pad2, +bc, relu
// block: 256 threads = 16x16 spatial tile; 16 output channels per block
// grid: (64 tiles, 4 co-groups, 4 batch)
// ---------------------------------------------------------------------------
__global__ __launch_bounds__(256) void conv1_kernel(
    const float* __restrict__ x, const float* __restrict__ Wc,
    const float* __restrict__ bc, float* __restrict__ xconv)
{
    const int tid = threadIdx.x;
    const int tx = tid & 15, ty = tid >> 4;
    const int tileId = blockIdx.x;            // 8x8 tiles of 16x16
    const int oh0 = (tileId >> 3) << 4;
    const int ow0 = (tileId & 7) << 4;
    const int cg  = blockIdx.y;               // 0..3 -> co = cg*16 + [0,16)
    const int n   = blockIdx.z;

    __shared__ __align__(16) float patch[35 * 35];
    __shared__ __align__(16) float wsm[16 * 28];   // rows padded 25 -> 28

    float acc[16];
#pragma unroll
    for (int i = 0; i < 16; ++i) acc[i] = 0.f;

    const int ihBase = 2 * oh0 - 2;
    const int iwBase = 2 * ow0 - 2;

    for (int ci = 0; ci < 32; ++ci) {
        // stage input patch (35x35), zero-padded at borders
        for (int idx = tid; idx < 35 * 35; idx += 256) {
            int py = idx / 35, px = idx % 35;
            int ih = ihBase + py, iw = iwBase + px;
            float v = 0.f;
            if (ih >= 0 && ih < 256 && iw >= 0 && iw < 256)
                v = x[((n * 32 + ci) * 256 + ih) * 256 + iw];
            patch[idx] = v;
        }
        // stage weights for 16 co, zero-pad to 28
        for (int idx = tid; idx < 16 * 28; idx += 256) {
            int co = idx / 28, t = idx % 28;
            wsm[idx] = (t < 25) ? Wc[((cg * 16 + co) * 32 + ci) * 25 + t] : 0.f;
        }
        __syncthreads();

        float p[28];
#pragma unroll
        for (int ky = 0; ky < 5; ++ky)
#pragma unroll
            for (int kx = 0; kx < 5; ++kx)
                p[ky * 5 + kx] = patch[(2 * ty + ky) * 35 + (2 * tx + kx)];
        p[25] = p[26] = p[27] = 0.f;

        const float4* wv = (const float4*)wsm;
#pragma unroll
        for (int co = 0; co < 16; ++co) {
            float s = 0.f;
#pragma unroll
            for (int t4 = 0; t4 < 7; ++t4) {
                float4 w4 = wv[co * 7 + t4];
                s += p[4 * t4 + 0] * w4.x + p[4 * t4 + 1] * w4.y
                   + p[4 * t4 + 2] * w4.z + p[4 * t4 + 3] * w4.w;
            }
            acc[co] += s;
        }
        __syncthreads();
    }

    const int oh = oh0 + ty, ow = ow0 + tx;
#pragma unroll
    for (int co = 0; co < 16; ++co) {
        float v = acc[co] + bc[cg * 16 + co];
        v = v > 0.f ? v : 0.f;
        xconv[((n * 64 + cg * 16 + co) * 128 + oh) * 128 + ow] = v;
    }
}

// ---------------------------------------------------------------------------
// gates + LSTM pointwise, fused.
// stacked input (virtual): ci<64 -> x_conv zero-padded by 1; ci>=64 ->
// prev_h[31+ih][31+iw].  Computes all 4 gates for 16 channels per block
// (acc[64]/thread), applies the cell math, writes hidden + interior of
// new_h/new_c.
// block: 256 = 16x16 spatial; grid: (64 tiles, 4 ch-groups, 4 batch)
// ---------------------------------------------------------------------------
__global__ __launch_bounds__(256) void gates_kernel(
    const float* __restrict__ xconv, const float* __restrict__ prev_h,
    const float* __restrict__ prev_c, const float* __restrict__ Wg,
    const float* __restrict__ bg, float* __restrict__ out)
{
    const int tid = threadIdx.x;
    const int tx = tid & 15, ty = tid >> 4;
    const int tileId = blockIdx.x;
    const int oh0 = (tileId >> 3) << 4;
    const int ow0 = (tileId & 7) << 4;
    const int cg  = blockIdx.y;               // channels cg*16 + [0,16)
    const int n   = blockIdx.z;

    __shared__ __align__(16) float patch[18 * 18];
    __shared__ __align__(16) float wsm[64 * 12];  // rows padded 9 -> 12

    float acc[64];
#pragma unroll
    for (int i = 0; i < 64; ++i) acc[i] = 0.f;

    for (int ci = 0; ci < 128; ++ci) {
        // stage 18x18 patch of stacked input
        for (int idx = tid; idx < 18 * 18; idx += 256) {
            int py = idx / 18, px = idx % 18;
            int ih = oh0 + py, iw = ow0 + px;    // stacked coords [0,130)
            float v;
            if (ci < 64) {
                int sy = ih - 1, sx = iw - 1;
                v = (sy >= 0 && sy < 128 && sx >= 0 && sx < 128)
                    ? xconv[((n * 64 + ci) * 128 + sy) * 128 + sx] : 0.f;
            } else {
                v = prev_h[((n * 64 + (ci - 64)) * 320 + (31 + ih)) * 320 + (31 + iw)];
            }
            patch[idx] = v;
        }
        // stage weights: j = gate*16 + ch  ->  co = gate*64 + cg*16 + ch
        for (int idx = tid; idx < 64 * 12; idx += 256) {
            int j = idx / 12, t = idx % 12;
            int g = j >> 4, ch = j & 15;
            int co = g * 64 + cg * 16 + ch;
            wsm[idx] = (t < 9) ? Wg[(co * 128 + ci) * 9 + t] : 0.f;
        }
        __syncthreads();

        float p[9];
#pragma unroll
        for (int ky = 0; ky < 3; ++ky)
#pragma unroll
            for (int kx = 0; kx < 3; ++kx)
                p[ky * 3 + kx] = patch[(ty + ky) * 18 + (tx + kx)];

        const float4* wv = (const float4*)wsm;
#pragma unroll
        for (int j = 0; j < 64; ++j) {
            float4 w0 = wv[j * 3 + 0];
            float4 w1 = wv[j * 3 + 1];
            float  w8 = wsm[j * 12 + 8];
            acc[j] += p[0] * w0.x + p[1] * w0.y + p[2] * w0.z + p[3] * w0.w
                    + p[4] * w1.x + p[5] * w1.y + p[6] * w1.z + p[7] * w1.w
                    + p[8] * w8;
        }
        __syncthreads();
    }

    const int oh = oh0 + ty, ow = ow0 + tx;
    float* outH  = out;
    float* outNH = out + OFF_NEWH;
    float* outNC = out + OFF_NEWC;

#pragma unroll
    for (int ch = 0; ch < 16; ++ch) {
        int c = cg * 16 + ch;
        float ig = acc[0 * 16 + ch] + bg[0 * 64 + c];
        float rg = acc[1 * 16 + ch] + bg[1 * 64 + c];
        float og = acc[2 * 16 + ch] + bg[2 * 64 + c];
        float gg = acc[3 * 16 + ch] + bg[3 * 64 + c];

        float prev_cell = prev_c[((n * 64 + c) * 320 + (32 + oh)) * 320 + (32 + ow)];
        float cell = sigm(rg) * prev_cell + sigm(ig) * tanhf(gg);
        float hid  = sigm(og) * tanhf(cell);

        outH [((n * 64 + c) * 128 + oh) * 128 + ow] = hid;
        outNH[((n * 64 + c) * 320 + (32 + oh)) * 320 + (32 + ow)] = hid;
        outNC[((n * 64 + c) * 320 + (32 + oh)) * 320 + (32 + ow)] = cell;
    }
}

// ---------------------------------------------------------------------------
// float4 grid-stride copy
// ---------------------------------------------------------------------------
__global__ __launch_bounds__(256) void copy_f4(
    const float4* __restrict__ src, float4* __restrict__ dst, int n4)
{
    int i = blockIdx.x * blockDim.x + threadIdx.x;
    int stride = gridDim.x * blockDim.x;
    for (; i < n4; i += stride) dst[i] = src[i];
}

extern "C" void kernel_launch(void* const* d_in, const int* in_sizes, int n_in,
                              void* d_out, int out_size, void* d_ws, size_t ws_size,
                              hipStream_t stream)
{
    const float* x      = (const float*)d_in[0];
    const float* prev_h = (const float*)d_in[1];
    const float* prev_c = (const float*)d_in[2];
    const float* Wc     = (const float*)d_in[3];
    const float* bc     = (const float*)d_in[4];
    const float* Wg     = (const float*)d_in[5];
    const float* bg     = (const float*)d_in[6];

    float* out   = (float*)d_out;
    float* xconv = (float*)d_ws;   // 4*64*128*128 f32 = 16.8 MB

    const int n4 = 26214400 / 4;
    copy_f4<<<2048, 256, 0, stream>>>((const float4*)prev_h, (float4*)(out + OFF_NEWH), n4);
    copy_f4<<<2048, 256, 0, stream>>>((const float4*)prev_c, (float4*)(out + OFF_NEWC), n4);

    conv1_kernel<<<dim3(64, 4, 4), 256, 0, stream>>>(x, Wc, bc, xconv);
    gates_kernel<<<dim3(64, 4, 4), 256, 0, stream>>>(xconv, prev_h, prev_c, Wg, bg, out);
}

// Round 6
// 622.795 us; speedup vs baseline: 3.8860x; 3.8860x over previous
//
#include <hip/hip_runtime.h>
#include <math.h>

// B=4, Cin=32, Cout=64
// x:(4,32,256,256) prev_h/c:(4,64,320,320) Wc:(64,32,5,5) Wg:(256,128,3,3)
// ey2=ex2=32, eh2=ew2=128, pad=1
// ws: xconv bf16 (4,64,128,128) | Wp bf16 [9][256][128] | Wp1 bf16 [25][64][32]
// out: hidden(4,64,128,128) | new_h(4,64,320,320) | new_c(4,64,320,320)

#define OFF_NEWH 4194304
#define OFF_NEWC 30408704

typedef __attribute__((ext_vector_type(8))) short bf16x8;
typedef __attribute__((ext_vector_type(4))) float f32x4;

__device__ __forceinline__ float sigm(float v) { return 1.0f / (1.0f + expf(-v)); }

__device__ __forceinline__ unsigned short f2bf(float f) {
    unsigned u = __builtin_bit_cast(unsigned, f);
    u = (u + 0x7FFFu + ((u >> 16) & 1u)) >> 16;
    return (unsigned short)u;
}

// ---------------------------------------------------------------------------
// pack Wc (64,32,5,5) f32 -> Wp1[tap(25)][co(64)][ci(32)] bf16 (51200)
// ---------------------------------------------------------------------------
__global__ __launch_bounds__(256) void pack_wc(
    const float* __restrict__ Wc, unsigned short* __restrict__ Wp1)
{
    int i = blockIdx.x * 256 + threadIdx.x;
    if (i < 51200) {
        int tap = i >> 11;
        int rem = i & 2047;
        int co  = rem >> 5;
        int ci  = rem & 31;
        Wp1[i] = f2bf(Wc[(co * 32 + ci) * 25 + tap]);
    }
}

// ---------------------------------------------------------------------------
// pack Wg (256,128,3,3) f32 -> Wp[tap(9)][co(256)][ci(128)] bf16 (294912)
// ---------------------------------------------------------------------------
__global__ __launch_bounds__(256) void pack_wg(
    const float* __restrict__ Wg, unsigned short* __restrict__ Wp)
{
    int i = blockIdx.x * 256 + threadIdx.x;
    if (i < 294912) {
        int tap = i >> 15;
        int rem = i & 32767;
        int co  = rem >> 7;
        int ci  = rem & 127;
        Wp[i] = f2bf(Wg[(co * 128 + ci) * 9 + tap]);
    }
}

// ---------------------------------------------------------------------------
// conv1 via MFMA: x (4,32,256,256) f32 -> xconv (4,64,128,128) bf16
// 5x5 stride2 pad2, +bc, relu.  GEMM: M=64 co, K=25x32, N=64 px (8x8 tile).
// Block 256 thr = 4 waves; wave wv owns co = wv*16+[0,16), all 64 pixels.
// LDS patch[pos=iyl*19+ixl][ci] stride 40 (16B-aligned, bank-balanced).
// grid: (256 tiles, 4 batch)
// ---------------------------------------------------------------------------
__global__ __launch_bounds__(256) void conv1_mfma(
    const float* __restrict__ x,
    const unsigned short* __restrict__ Wp1,   // bf16 [25][64][32]
    const float* __restrict__ bc,
    unsigned short* __restrict__ xconv)
{
    __shared__ __align__(16) unsigned short patch[361 * 40];   // 28.9 KB

    const int tid  = threadIdx.x;
    const int lane = tid & 63;
    const int wv   = tid >> 6;
    const int l15  = lane & 15;
    const int g    = lane >> 4;

    const int tile = blockIdx.x;      // 16x16 tiles of 8x8 pixels
    const int ty0  = (tile >> 4) << 3;
    const int tx0  = (tile & 15) << 3;
    const int n    = blockIdx.y;

    const int iyBase = 2 * ty0 - 2;
    const int ixBase = 2 * tx0 - 2;

    // stage 19x19 x 32ci patch, f32 -> bf16, zero-padded at borders
    for (int r = tid; r < 608; r += 256) {     // r = ci*19 + iyl
        int ci  = r / 19;
        int iyl = r - ci * 19;
        int iy  = iyBase + iyl;
        unsigned short* dst = patch + iyl * (19 * 40) + ci;
        if (iy >= 0 && iy < 256) {
            const float* src = x + ((n * 32 + ci) * 256 + iy) * 256;
#pragma unroll
            for (int ixl = 0; ixl < 19; ++ixl) {
                int ix = ixBase + ixl;
                unsigned short v = 0;
                if (ix >= 0 && ix < 256) v = f2bf(src[ix]);
                dst[ixl * 40] = v;
            }
        } else {
#pragma unroll
            for (int ixl = 0; ixl < 19; ++ixl) dst[ixl * 40] = 0;
        }
    }
    __syncthreads();

    f32x4 acc[4];
#pragma unroll
    for (int cf = 0; cf < 4; ++cf)
#pragma unroll
        for (int e = 0; e < 4; ++e) acc[cf][e] = 0.f;

    // A: row = l15 -> co = wv*16+l15; k = g*8 + [0,8) within 32-ci chunk
    const unsigned short* Abase = Wp1 + (wv * 16 + l15) * 32 + g * 8;
    // B: col = l15 -> pixel; per-lane spatial base (pixel p = cf*16+l15)
    const int posBase = (2 * (l15 >> 3)) * 19 + 2 * (l15 & 7);
    const unsigned short* Bbase = patch + posBase * 40 + g * 8;

#pragma unroll
    for (int tap = 0; tap < 25; ++tap) {
        const int ky = tap / 5, kx = tap % 5;
        bf16x8 a = *(const bf16x8*)(Abase + tap * 2048);
        const unsigned short* Bt = Bbase + (ky * 19 + kx) * 40;
#pragma unroll
        for (int cf = 0; cf < 4; ++cf) {
            bf16x8 b = *(const bf16x8*)(Bt + cf * (76 * 40));  // iy_l += 4 per cf
            acc[cf] = __builtin_amdgcn_mfma_f32_16x16x32_bf16(a, b, acc[cf], 0, 0, 0);
        }
    }

    // epilogue: D col = l15 = pixel, row = g*4+r -> co
#pragma unroll
    for (int cf = 0; cf < 4; ++cf) {
        int p  = cf * 16 + l15;
        int oh = ty0 + (p >> 3);
        int ow = tx0 + (p & 7);
#pragma unroll
        for (int r = 0; r < 4; ++r) {
            int co = wv * 16 + g * 4 + r;
            float v = acc[cf][r] + bc[co];
            v = fmaxf(v, 0.f);
            xconv[((n * 64 + co) * 128 + oh) * 128 + ow] = f2bf(v);
        }
    }
}

// ---------------------------------------------------------------------------
// gates conv (3x3, pad0 over virtual 130x130 stacked input) + LSTM epilogue,
// via bf16 MFMA. Block: 256 thr = 4 waves; tile = 8x8 pixels, M=256 gates.
// K order: tap-major (9 taps x 4 ci-chunks of 32).
// LDS patch[pos=y*10+x][ci] stride 136 (bank-conflict-free b128).
// Wave wv handles channels wv*16+[0,16) for ALL 4 gates -> in-register LSTM.
// grid: (256 tiles, 4 batch)
// ---------------------------------------------------------------------------
__global__ __launch_bounds__(256) void gates_mfma(
    const unsigned short* __restrict__ xconv,   // bf16 (4,64,128,128)
    const float* __restrict__ prev_h,
    const float* __restrict__ prev_c,
    const unsigned short* __restrict__ Wp,      // bf16 [9][256][128]
    const float* __restrict__ bg,
    float* __restrict__ out)
{
    __shared__ __align__(16) unsigned short patch[100 * 136];   // 27.2 KB

    const int tid  = threadIdx.x;
    const int lane = tid & 63;
    const int wv   = tid >> 6;        // wave 0..3
    const int l15  = lane & 15;
    const int g    = lane >> 4;       // 0..3

    const int tile = blockIdx.x;      // 16x16 tiles of 8x8 pixels
    const int ty0  = (tile >> 4) << 3;
    const int tx0  = (tile & 15) << 3;
    const int n    = blockIdx.y;

    // ---- stage stacked patch (10x10 x 128ci), transposed to [pos][ci] ----
    for (int r = tid; r < 1280; r += 256) {      // r = ci*10 + y
        int ci = r / 10;
        int y  = r - ci * 10;
        int sy = ty0 + y;
        if (ci < 64) {
            int yy = sy - 1;
            const unsigned short* src = xconv + (((n * 64 + ci) * 128 + yy) * 128);
            bool yok = (yy >= 0 && yy < 128);
#pragma unroll
            for (int xx = 0; xx < 10; ++xx) {
                int sx = tx0 + xx - 1;
                unsigned short v = 0;
                if (yok && sx >= 0 && sx < 128) v = src[sx];
                patch[(y * 10 + xx) * 136 + ci] = v;
            }
        } else {
            const float* src = prev_h + ((n * 64 + (ci - 64)) * 320 + (31 + sy)) * 320 + 31 + tx0;
#pragma unroll
            for (int xx = 0; xx < 10; ++xx)
                patch[(y * 10 + xx) * 136 + ci] = f2bf(src[xx]);
        }
    }
    __syncthreads();

    f32x4 acc[4][4];
#pragma unroll
    for (int i = 0; i < 4; ++i)
#pragma unroll
        for (int j = 0; j < 4; ++j)
#pragma unroll
            for (int e = 0; e < 4; ++e) acc[i][j][e] = 0.f;

    const int arow = wv * 16 + l15;                 // channel row within gate
    const unsigned short* Abase = Wp + arow * 128 + g * 8;
    const int bb = (l15 >> 3) * 10 + (l15 & 7);     // per-lane spatial base

    for (int tap = 0; tap < 9; ++tap) {
        const int ky = tap / 3;
        const int kx = tap - ky * 3;
        const int koff = ky * 10 + kx;
        const unsigned short* At = Abase + tap * 32768;
        const unsigned short* Bt = patch + (bb + koff) * 136 + g * 8;
#pragma unroll
        for (int chunk = 0; chunk < 4; ++chunk) {
            bf16x8 a0 = *(const bf16x8*)(At + 0 * 8192 + chunk * 32);
            bf16x8 a1 = *(const bf16x8*)(At + 1 * 8192 + chunk * 32);
            bf16x8 a2 = *(const bf16x8*)(At + 2 * 8192 + chunk * 32);
            bf16x8 a3 = *(const bf16x8*)(At + 3 * 8192 + chunk * 32);
            const unsigned short* pb = Bt + chunk * 32;
            bf16x8 b0 = *(const bf16x8*)(pb + 0 * 2720);   // cf*20*136
            bf16x8 b1 = *(const bf16x8*)(pb + 1 * 2720);
            bf16x8 b2 = *(const bf16x8*)(pb + 2 * 2720);
            bf16x8 b3 = *(const bf16x8*)(pb + 3 * 2720);
            acc[0][0] = __builtin_amdgcn_mfma_f32_16x16x32_bf16(a0, b0, acc[0][0], 0, 0, 0);
            acc[0][1] = __builtin_amdgcn_mfma_f32_16x16x32_bf16(a0, b1, acc[0][1], 0, 0, 0);
            acc[0][2] = __builtin_amdgcn_mfma_f32_16x16x32_bf16(a0, b2, acc[0][2], 0, 0, 0);
            acc[0][3] = __builtin_amdgcn_mfma_f32_16x16x32_bf16(a0, b3, acc[0][3], 0, 0, 0);
            acc[1][0] = __builtin_amdgcn_mfma_f32_16x16x32_bf16(a1, b0, acc[1][0], 0, 0, 0);
            acc[1][1] = __builtin_amdgcn_mfma_f32_16x16x32_bf16(a1, b1, acc[1][1], 0, 0, 0);
            acc[1][2] = __builtin_amdgcn_mfma_f32_16x16x32_bf16(a1, b2, acc[1][2], 0, 0, 0);
            acc[1][3] = __builtin_amdgcn_mfma_f32_16x16x32_bf16(a1, b3, acc[1][3], 0, 0, 0);
            acc[2][0] = __builtin_amdgcn_mfma_f32_16x16x32_bf16(a2, b0, acc[2][0], 0, 0, 0);
            acc[2][1] = __builtin_amdgcn_mfma_f32_16x16x32_bf16(a2, b1, acc[2][1], 0, 0, 0);
            acc[2][2] = __builtin_amdgcn_mfma_f32_16x16x32_bf16(a2, b2, acc[2][2], 0, 0, 0);
            acc[2][3] = __builtin_amdgcn_mfma_f32_16x16x32_bf16(a2, b3, acc[2][3], 0, 0, 0);
            acc[3][0] = __builtin_amdgcn_mfma_f32_16x16x32_bf16(a3, b0, acc[3][0], 0, 0, 0);
            acc[3][1] = __builtin_amdgcn_mfma_f32_16x16x32_bf16(a3, b1, acc[3][1], 0, 0, 0);
            acc[3][2] = __builtin_amdgcn_mfma_f32_16x16x32_bf16(a3, b2, acc[3][2], 0, 0, 0);
            acc[3][3] = __builtin_amdgcn_mfma_f32_16x16x32_bf16(a3, b3, acc[3][3], 0, 0, 0);
        }
    }

    // ---- fused LSTM epilogue, fully in-register ----
#pragma unroll
    for (int cf = 0; cf < 4; ++cf) {
        int p  = cf * 16 + l15;
        int oh = ty0 + (p >> 3);
        int ow = tx0 + (p & 7);
#pragma unroll
        for (int r = 0; r < 4; ++r) {
            int c = wv * 16 + g * 4 + r;
            float ig = acc[0][cf][r] + bg[c];
            float rg = acc[1][cf][r] + bg[64 + c];
            float og = acc[2][cf][r] + bg[128 + c];
            float gg = acc[3][cf][r] + bg[192 + c];
            float pc = prev_c[((n * 64 + c) * 320 + (32 + oh)) * 320 + (32 + ow)];
            float cell = sigm(rg) * pc + sigm(ig) * tanhf(gg);
            float hid  = sigm(og) * tanhf(cell);
            out[((n * 64 + c) * 128 + oh) * 128 + ow] = hid;
            out[OFF_NEWH + ((n * 64 + c) * 320 + (32 + oh)) * 320 + (32 + ow)] = hid;
            out[OFF_NEWC + ((n * 64 + c) * 320 + (32 + oh)) * 320 + (32 + ow)] = cell;
        }
    }
}

// ---------------------------------------------------------------------------
__global__ __launch_bounds__(256) void copy_f4(
    const float4* __restrict__ src, float4* __restrict__ dst, int n4)
{
    int i = blockIdx.x * blockDim.x + threadIdx.x;
    int stride = gridDim.x * blockDim.x;
    for (; i < n4; i += stride) dst[i] = src[i];
}

extern "C" void kernel_launch(void* const* d_in, const int* in_sizes, int n_in,
                              void* d_out, int out_size, void* d_ws, size_t ws_size,
                              hipStream_t stream)
{
    const float* x      = (const float*)d_in[0];
    const float* prev_h = (const float*)d_in[1];
    const float* prev_c = (const float*)d_in[2];
    const float* Wc     = (const float*)d_in[3];
    const float* bc     = (const float*)d_in[4];
    const float* Wg     = (const float*)d_in[5];
    const float* bg     = (const float*)d_in[6];

    float* out = (float*)d_out;
    unsigned short* xconv_bf = (unsigned short*)d_ws;          // 4194304 u16
    unsigned short* Wp       = xconv_bf + 4194304;             // 294912 u16
    unsigned short* Wp1      = Wp + 294912;                    // 51200 u16

    const int n4 = 26214400 / 4;
    copy_f4<<<2048, 256, 0, stream>>>((const float4*)prev_h, (float4*)(out + OFF_NEWH), n4);
    copy_f4<<<2048, 256, 0, stream>>>((const float4*)prev_c, (float4*)(out + OFF_NEWC), n4);

    pack_wg<<<1152, 256, 0, stream>>>(Wg, Wp);
    pack_wc<<<200, 256, 0, stream>>>(Wc, Wp1);
    conv1_mfma<<<dim3(256, 4), 256, 0, stream>>>(x, Wp1, bc, xconv_bf);
    gates_mfma<<<dim3(256, 4), 256, 0, stream>>>(xconv_bf, prev_h, prev_c, Wp, bg, out);
}

// Round 7
// 621.269 us; speedup vs baseline: 3.8955x; 1.0025x over previous
//
#include <hip/hip_runtime.h>
#include <math.h>

// B=4, Cin=32, Cout=64
// x:(4,32,256,256) prev_h/c:(4,64,320,320) Wc:(64,32,5,5) Wg:(256,128,3,3)
// ey2=ex2=32, eh2=ew2=128, pad=1
// ws (u16 units):
//   S   [4][130][130][128] bf16  @ 0         (8,652,800)  stacked gates input
//   Xp  [4][260][260][32]  bf16  @ 8652800   (8,652,800)  padded NHWC x
//   Wp  [9][256][128]      bf16  @ 17305600  (294,912)    gates weights
//   Wp1 [25][64][32]       bf16  @ 17600512  (51,200)     conv1 weights
// out: hidden(4,64,128,128) | new_h(4,64,320,320) | new_c(4,64,320,320)

#define OFF_NEWH 4194304
#define OFF_NEWC 30408704
#define S_ELEMS  8652800
#define XP_OFF   8652800
#define WP_OFF   17305600
#define WP1_OFF  17600512

typedef __attribute__((ext_vector_type(8))) short bf16x8;
typedef __attribute__((ext_vector_type(4))) float f32x4;

__device__ __forceinline__ float sigm(float v) { return 1.0f / (1.0f + expf(-v)); }

__device__ __forceinline__ unsigned short f2bf(float f) {
    unsigned u = __builtin_bit_cast(unsigned, f);
    u = (u + 0x7FFFu + ((u >> 16) & 1u)) >> 16;
    return (unsigned short)u;
}
__device__ __forceinline__ unsigned pack2(float lo, float hi) {
    return (unsigned)f2bf(lo) | ((unsigned)f2bf(hi) << 16);
}

// ---------------------------------------------------------------------------
// pack Wc (64,32,5,5) f32 -> Wp1[tap(25)][co(64)][ci(32)] bf16
// ---------------------------------------------------------------------------
__global__ __launch_bounds__(256) void pack_wc(
    const float* __restrict__ Wc, unsigned short* __restrict__ Wp1)
{
    int i = blockIdx.x * 256 + threadIdx.x;
    if (i < 51200) {
        int tap = i >> 11;
        int rem = i & 2047;
        int co  = rem >> 5;
        int ci  = rem & 31;
        Wp1[i] = f2bf(Wc[(co * 32 + ci) * 25 + tap]);
    }
}

// ---------------------------------------------------------------------------
// pack Wg (256,128,3,3) f32 -> Wp[tap(9)][co(256)][ci(128)] bf16
// ---------------------------------------------------------------------------
__global__ __launch_bounds__(256) void pack_wg(
    const float* __restrict__ Wg, unsigned short* __restrict__ Wp)
{
    int i = blockIdx.x * 256 + threadIdx.x;
    if (i < 294912) {
        int tap = i >> 15;
        int rem = i & 32767;
        int co  = rem >> 7;
        int ci  = rem & 127;
        Wp[i] = f2bf(Wg[(co * 128 + ci) * 9 + tap]);
    }
}

// ---------------------------------------------------------------------------
// xpose_x: x (4,32,256,256) f32 NCHW -> Xp (4,260,260,32) bf16 NHWC,
// interior at (y+2, x+2); ring pre-zeroed by memset.
// grid (256 y, 4 n), block 256.
// ---------------------------------------------------------------------------
__global__ __launch_bounds__(256) void xpose_x(
    const float* __restrict__ x, unsigned short* __restrict__ Xp)
{
    __shared__ __align__(16) float lds[32 * 260];   // stride 260: banks (4c+px)%32
    const int y = blockIdx.x, n = blockIdx.y, tid = threadIdx.x;

    for (int u = tid; u < 2048; u += 256) {          // 32c x 64 quads
        int c = u >> 6, x4 = (u & 63) << 2;
        float4 v = *(const float4*)(x + (((n * 32 + c) * 256 + y) << 8) + x4);
        *(float4*)(&lds[c * 260 + x4]) = v;
    }
    __syncthreads();

    const int px = tid;                              // 0..255
    unsigned short* dst = Xp + (((n * 260) + (y + 2)) * 260 + (px + 2)) * 32;
#pragma unroll
    for (int q = 0; q < 4; ++q) {
        uint4 w;
        w.x = pack2(lds[(q * 8 + 0) * 260 + px], lds[(q * 8 + 1) * 260 + px]);
        w.y = pack2(lds[(q * 8 + 2) * 260 + px], lds[(q * 8 + 3) * 260 + px]);
        w.z = pack2(lds[(q * 8 + 4) * 260 + px], lds[(q * 8 + 5) * 260 + px]);
        w.w = pack2(lds[(q * 8 + 6) * 260 + px], lds[(q * 8 + 7) * 260 + px]);
        *(uint4*)(dst + q * 8) = w;
    }
}

// ---------------------------------------------------------------------------
// hconv: prev_h f32 -> S[n][sy][sx][64+c] bf16 (c=0..63), sy,sx in [0,130)
// source row = prev_h[n][c][31+sy][31+sx].  grid (130 sy, 4 n).
// ---------------------------------------------------------------------------
__global__ __launch_bounds__(256) void hconv(
    const float* __restrict__ prev_h, unsigned short* __restrict__ S)
{
    const int sy = blockIdx.x, n = blockIdx.y, tid = threadIdx.x;
    for (int u = tid; u < 1040; u += 256) {          // 130 px x 8 chunks
        int px = u >> 3, ch = u & 7;
        const float* src = prev_h + (((n * 64 + ch * 8) * 320 + (31 + sy)) * 320) + 31 + px;
        uint4 w;
        w.x = pack2(src[0 * 102400], src[1 * 102400]);
        w.y = pack2(src[2 * 102400], src[3 * 102400]);
        w.z = pack2(src[4 * 102400], src[5 * 102400]);
        w.w = pack2(src[6 * 102400], src[7 * 102400]);
        *(uint4*)(S + (((n * 130 + sy) * 130 + px) << 7) + 64 + ch * 8) = w;
    }
}

// ---------------------------------------------------------------------------
// conv1 via MFMA: Xp bf16 NHWC -> S[...][ci 0..63] (x_conv, relu, +bc),
// writing at (1+oh, 1+ow).  GEMM: M=64 co, K=25x32, N=64 px (8x8 tile).
// LDS patch[pos=iyl*19+ixl][ci] stride 40 u16 (verified conflict-free).
// grid: (256 tiles, 4 batch)
// ---------------------------------------------------------------------------
__global__ __launch_bounds__(256) void conv1_mfma(
    const unsigned short* __restrict__ Xp,
    const unsigned short* __restrict__ Wp1,
    const float* __restrict__ bc,
    unsigned short* __restrict__ S)
{
    __shared__ __align__(16) unsigned short patch[361 * 40];   // 28.9 KB

    const int tid  = threadIdx.x;
    const int lane = tid & 63;
    const int wv   = tid >> 6;
    const int l15  = lane & 15;
    const int g    = lane >> 4;

    const int tile = blockIdx.x;
    const int ty0  = (tile >> 4) << 3;
    const int tx0  = (tile & 15) << 3;
    const int n    = blockIdx.y;

    // stage 19x19 pos x 32ci, all b128 (Xp padded: iy = 2*ty0+iyl in [0,258])
    for (int u = tid; u < 1444; u += 256) {          // 361 pos x 4 chunks
        int pos = u >> 2, ch = u & 3;
        int iyl = pos / 19, ixl = pos - iyl * 19;
        const unsigned short* src =
            Xp + (((n * 260) + 2 * ty0 + iyl) * 260 + 2 * tx0 + ixl) * 32 + ch * 8;
        *(bf16x8*)(&patch[pos * 40 + ch * 8]) = *(const bf16x8*)src;
    }
    __syncthreads();

    f32x4 acc[4];
#pragma unroll
    for (int cf = 0; cf < 4; ++cf)
#pragma unroll
        for (int e = 0; e < 4; ++e) acc[cf][e] = 0.f;

    const unsigned short* Abase = Wp1 + (wv * 16 + l15) * 32 + g * 8;
    const int posBase = (2 * (l15 >> 3)) * 19 + 2 * (l15 & 7);
    const unsigned short* Bbase = patch + posBase * 40 + g * 8;

#pragma unroll
    for (int tap = 0; tap < 25; ++tap) {
        const int ky = tap / 5, kx = tap % 5;
        bf16x8 a = *(const bf16x8*)(Abase + tap * 2048);
        const unsigned short* Bt = Bbase + (ky * 19 + kx) * 40;
#pragma unroll
        for (int cf = 0; cf < 4; ++cf) {
            bf16x8 b = *(const bf16x8*)(Bt + cf * (76 * 40));
            acc[cf] = __builtin_amdgcn_mfma_f32_16x16x32_bf16(a, b, acc[cf], 0, 0, 0);
        }
    }

    // epilogue: 4 contiguous co per thread -> uint2 write into S interior
#pragma unroll
    for (int cf = 0; cf < 4; ++cf) {
        int p  = cf * 16 + l15;
        int oh = ty0 + (p >> 3);
        int ow = tx0 + (p & 7);
        int co = wv * 16 + g * 4;
        float v0 = fmaxf(acc[cf][0] + bc[co + 0], 0.f);
        float v1 = fmaxf(acc[cf][1] + bc[co + 1], 0.f);
        float v2 = fmaxf(acc[cf][2] + bc[co + 2], 0.f);
        float v3 = fmaxf(acc[cf][3] + bc[co + 3], 0.f);
        uint2 w;
        w.x = pack2(v0, v1);
        w.y = pack2(v2, v3);
        *(uint2*)(S + (((n * 130 + 1 + oh) * 130 + 1 + ow) << 7) + co) = w;
    }
}

// ---------------------------------------------------------------------------
// gates conv (3x3 over S 130x130x128 NHWC) + fused LSTM epilogue, bf16 MFMA.
// Block: 4 waves; tile 8x8 px; M=256 gates; K=9 taps x 128ci.
// LDS patch[pos=y*10+x][ci] stride 136 u16 (verified conflict-free).
// grid: (256 tiles, 4 batch)
// ---------------------------------------------------------------------------
__global__ __launch_bounds__(256) void gates_mfma(
    const unsigned short* __restrict__ S,
    const float* __restrict__ prev_c,
    const unsigned short* __restrict__ Wp,
    const float* __restrict__ bg,
    float* __restrict__ out)
{
    __shared__ __align__(16) unsigned short patch[100 * 136];   // 27.2 KB

    const int tid  = threadIdx.x;
    const int lane = tid & 63;
    const int wv   = tid >> 6;
    const int l15  = lane & 15;
    const int g    = lane >> 4;

    const int tile = blockIdx.x;
    const int ty0  = (tile >> 4) << 3;
    const int tx0  = (tile & 15) << 3;
    const int n    = blockIdx.y;

    // stage 10x10 pos x 128ci, all b128
    for (int u = tid; u < 1600; u += 256) {          // 100 pos x 16 chunks
        int pos = u >> 4, ch = u & 15;
        int y = pos / 10, xx = pos - y * 10;
        const unsigned short* src =
            S + (((n * 130 + ty0 + y) * 130 + tx0 + xx) << 7) + ch * 8;
        *(bf16x8*)(&patch[pos * 136 + ch * 8]) = *(const bf16x8*)src;
    }
    __syncthreads();

    f32x4 acc[4][4];
#pragma unroll
    for (int i = 0; i < 4; ++i)
#pragma unroll
        for (int j = 0; j < 4; ++j)
#pragma unroll
            for (int e = 0; e < 4; ++e) acc[i][j][e] = 0.f;

    const unsigned short* Abase = Wp + (wv * 16 + l15) * 128 + g * 8;
    const int bb = (l15 >> 3) * 10 + (l15 & 7);

    for (int tap = 0; tap < 9; ++tap) {
        const int ky = tap / 3;
        const int kx = tap - ky * 3;
        const int koff = ky * 10 + kx;
        const unsigned short* At = Abase + tap * 32768;
        const unsigned short* Bt = patch + (bb + koff) * 136 + g * 8;
#pragma unroll
        for (int chunk = 0; chunk < 4; ++chunk) {
            bf16x8 a0 = *(const bf16x8*)(At + 0 * 8192 + chunk * 32);
            bf16x8 a1 = *(const bf16x8*)(At + 1 * 8192 + chunk * 32);
            bf16x8 a2 = *(const bf16x8*)(At + 2 * 8192 + chunk * 32);
            bf16x8 a3 = *(const bf16x8*)(At + 3 * 8192 + chunk * 32);
            const unsigned short* pb = Bt + chunk * 32;
            bf16x8 b0 = *(const bf16x8*)(pb + 0 * 2720);
            bf16x8 b1 = *(const bf16x8*)(pb + 1 * 2720);
            bf16x8 b2 = *(const bf16x8*)(pb + 2 * 2720);
            bf16x8 b3 = *(const bf16x8*)(pb + 3 * 2720);
            acc[0][0] = __builtin_amdgcn_mfma_f32_16x16x32_bf16(a0, b0, acc[0][0], 0, 0, 0);
            acc[0][1] = __builtin_amdgcn_mfma_f32_16x16x32_bf16(a0, b1, acc[0][1], 0, 0, 0);
            acc[0][2] = __builtin_amdgcn_mfma_f32_16x16x32_bf16(a0, b2, acc[0][2], 0, 0, 0);
            acc[0][3] = __builtin_amdgcn_mfma_f32_16x16x32_bf16(a0, b3, acc[0][3], 0, 0, 0);
            acc[1][0] = __builtin_amdgcn_mfma_f32_16x16x32_bf16(a1, b0, acc[1][0], 0, 0, 0);
            acc[1][1] = __builtin_amdgcn_mfma_f32_16x16x32_bf16(a1, b1, acc[1][1], 0, 0, 0);
            acc[1][2] = __builtin_amdgcn_mfma_f32_16x16x32_bf16(a1, b2, acc[1][2], 0, 0, 0);
            acc[1][3] = __builtin_amdgcn_mfma_f32_16x16x32_bf16(a1, b3, acc[1][3], 0, 0, 0);
            acc[2][0] = __builtin_amdgcn_mfma_f32_16x16x32_bf16(a2, b0, acc[2][0], 0, 0, 0);
            acc[2][1] = __builtin_amdgcn_mfma_f32_16x16x32_bf16(a2, b1, acc[2][1], 0, 0, 0);
            acc[2][2] = __builtin_amdgcn_mfma_f32_16x16x32_bf16(a2, b2, acc[2][2], 0, 0, 0);
            acc[2][3] = __builtin_amdgcn_mfma_f32_16x16x32_bf16(a2, b3, acc[2][3], 0, 0, 0);
            acc[3][0] = __builtin_amdgcn_mfma_f32_16x16x32_bf16(a3, b0, acc[3][0], 0, 0, 0);
            acc[3][1] = __builtin_amdgcn_mfma_f32_16x16x32_bf16(a3, b1, acc[3][1], 0, 0, 0);
            acc[3][2] = __builtin_amdgcn_mfma_f32_16x16x32_bf16(a3, b2, acc[3][2], 0, 0, 0);
            acc[3][3] = __builtin_amdgcn_mfma_f32_16x16x32_bf16(a3, b3, acc[3][3], 0, 0, 0);
        }
    }

    // fused LSTM epilogue
#pragma unroll
    for (int cf = 0; cf < 4; ++cf) {
        int p  = cf * 16 + l15;
        int oh = ty0 + (p >> 3);
        int ow = tx0 + (p & 7);
#pragma unroll
        for (int r = 0; r < 4; ++r) {
            int c = wv * 16 + g * 4 + r;
            float ig = acc[0][cf][r] + bg[c];
            float rg = acc[1][cf][r] + bg[64 + c];
            float og = acc[2][cf][r] + bg[128 + c];
            float gg = acc[3][cf][r] + bg[192 + c];
            float pc = prev_c[((n * 64 + c) * 320 + (32 + oh)) * 320 + (32 + ow)];
            float cell = sigm(rg) * pc + sigm(ig) * tanhf(gg);
            float hid  = sigm(og) * tanhf(cell);
            out[((n * 64 + c) * 128 + oh) * 128 + ow] = hid;
            out[OFF_NEWH + ((n * 64 + c) * 320 + (32 + oh)) * 320 + (32 + ow)] = hid;
            out[OFF_NEWC + ((n * 64 + c) * 320 + (32 + oh)) * 320 + (32 + ow)] = cell;
        }
    }
}

// ---------------------------------------------------------------------------
__global__ __launch_bounds__(256) void copy_f4(
    const float4* __restrict__ src, float4* __restrict__ dst, int n4)
{
    int i = blockIdx.x * blockDim.x + threadIdx.x;
    int stride = gridDim.x * blockDim.x;
    for (; i < n4; i += stride) dst[i] = src[i];
}

extern "C" void kernel_launch(void* const* d_in, const int* in_sizes, int n_in,
                              void* d_out, int out_size, void* d_ws, size_t ws_size,
                              hipStream_t stream)
{
    const float* x      = (const float*)d_in[0];
    const float* prev_h = (const float*)d_in[1];
    const float* prev_c = (const float*)d_in[2];
    const float* Wc     = (const float*)d_in[3];
    const float* bc     = (const float*)d_in[4];
    const float* Wg     = (const float*)d_in[5];
    const float* bg     = (const float*)d_in[6];

    float* out = (float*)d_out;
    unsigned short* S   = (unsigned short*)d_ws;
    unsigned short* Xp  = S + XP_OFF - 0;          // S + 8,652,800
    unsigned short* Wp  = S + WP_OFF;
    unsigned short* Wp1 = S + WP1_OFF;
    Xp = S + S_ELEMS;

    // zero padding rings (whole buffers, ~6 us)
    hipMemsetAsync(S,  0, (size_t)S_ELEMS * 2, stream);
    hipMemsetAsync(Xp, 0, (size_t)S_ELEMS * 2, stream);

    const int n4 = 26214400 / 4;
    copy_f4<<<2048, 256, 0, stream>>>((const float4*)prev_h, (float4*)(out + OFF_NEWH), n4);
    copy_f4<<<2048, 256, 0, stream>>>((const float4*)prev_c, (float4*)(out + OFF_NEWC), n4);

    pack_wg<<<1152, 256, 0, stream>>>(Wg, Wp);
    pack_wc<<<200, 256, 0, stream>>>(Wc, Wp1);
    xpose_x<<<dim3(256, 4), 256, 0, stream>>>(x, Xp);
    hconv<<<dim3(130, 4), 256, 0, stream>>>(prev_h, S);
    conv1_mfma<<<dim3(256, 4), 256, 0, stream>>>(Xp, Wp1, bc, S);
    gates_mfma<<<dim3(256, 4), 256, 0, stream>>>(S, prev_c, Wp, bg, out);
}

// Round 8
// 555.951 us; speedup vs baseline: 4.3532x; 1.1175x over previous
//
#include <hip/hip_runtime.h>
#include <math.h>

// B=4, Cin=32, Cout=64
// x:(4,32,256,256) prev_h/c:(4,64,320,320) Wc:(64,32,5,5) Wg:(256,128,3,3)
// ws (u16 units):
//   S   [4][130][130][128] bf16  @ 0         stacked gates input (NHWC)
//   Xp  [4][260][260][32]  bf16  @ 8652800   padded NHWC x
//   WpF fragment-ordered gates weights @ 17305600 (294912)
//   Wp1 [25][64][32] conv1 weights     @ 17600512 (51200)
// out: hidden(4,64,128,128) | new_h(4,64,320,320) | new_c(4,64,320,320)

#define OFF_NEWH 4194304
#define OFF_NEWC 30408704
#define S_ELEMS  8652800
#define WP_OFF   17305600
#define WP1_OFF  17600512

typedef __attribute__((ext_vector_type(8))) short bf16x8;
typedef __attribute__((ext_vector_type(4))) float f32x4;

__device__ __forceinline__ float sigm(float v) { return 1.0f / (1.0f + expf(-v)); }

__device__ __forceinline__ unsigned short f2bf(float f) {
    unsigned u = __builtin_bit_cast(unsigned, f);
    u = (u + 0x7FFFu + ((u >> 16) & 1u)) >> 16;
    return (unsigned short)u;
}
__device__ __forceinline__ unsigned pack2(float lo, float hi) {
    return (unsigned)f2bf(lo) | ((unsigned)f2bf(hi) << 16);
}

// ---------------------------------------------------------------------------
// pack Wc (64,32,5,5) f32 -> Wp1[tap(25)][co(64)][ci(32)] bf16
// ---------------------------------------------------------------------------
__global__ __launch_bounds__(256) void pack_wc(
    const float* __restrict__ Wc, unsigned short* __restrict__ Wp1)
{
    int i = blockIdx.x * 256 + threadIdx.x;
    if (i < 51200) {
        int tap = i >> 11;
        int rem = i & 2047;
        int co  = rem >> 5;
        int ci  = rem & 31;
        Wp1[i] = f2bf(Wc[(co * 32 + ci) * 25 + tap]);
    }
}

// ---------------------------------------------------------------------------
// pack Wg -> FRAGMENT-ORDERED WpF:
// u16 idx = ((((tap*4+chunk)*4 + i)*4 + wv)*64 + lane)*8 + e
// where co = i*64 + wv*16 + (lane&15), ci = chunk*32 + (lane>>4)*8 + e.
// Kernel A-load becomes WpV[(tap*4+chunk)*1024 + i*256 + tid] -> fully
// coalesced (64 lanes = 1KB contiguous).
// ---------------------------------------------------------------------------
__global__ __launch_bounds__(256) void pack_wg(
    const float* __restrict__ Wg, unsigned short* __restrict__ Wp)
{
    int idx = blockIdx.x * 256 + threadIdx.x;
    if (idx < 294912) {
        int e     = idx & 7;
        int lane  = (idx >> 3) & 63;
        int wv2   = (idx >> 9) & 3;
        int i     = (idx >> 11) & 3;
        int chunk = (idx >> 13) & 3;
        int tap   = idx >> 15;
        int l15 = lane & 15, g = lane >> 4;
        int co = i * 64 + wv2 * 16 + l15;
        int ci = chunk * 32 + g * 8 + e;
        Wp[idx] = f2bf(Wg[(co * 128 + ci) * 9 + tap]);
    }
}

// ---------------------------------------------------------------------------
// xpose_x: x (4,32,256,256) f32 NCHW -> Xp (4,260,260,32) bf16 NHWC,
// interior at (y+2, x+2); ring pre-zeroed by memset.
// ---------------------------------------------------------------------------
__global__ __launch_bounds__(256) void xpose_x(
    const float* __restrict__ x, unsigned short* __restrict__ Xp)
{
    __shared__ __align__(16) float lds[32 * 260];
    const int y = blockIdx.x, n = blockIdx.y, tid = threadIdx.x;

    for (int u = tid; u < 2048; u += 256) {
        int c = u >> 6, x4 = (u & 63) << 2;
        float4 v = *(const float4*)(x + (((n * 32 + c) * 256 + y) << 8) + x4);
        *(float4*)(&lds[c * 260 + x4]) = v;
    }
    __syncthreads();

    const int px = tid;
    unsigned short* dst = Xp + (((n * 260) + (y + 2)) * 260 + (px + 2)) * 32;
#pragma unroll
    for (int q = 0; q < 4; ++q) {
        uint4 w;
        w.x = pack2(lds[(q * 8 + 0) * 260 + px], lds[(q * 8 + 1) * 260 + px]);
        w.y = pack2(lds[(q * 8 + 2) * 260 + px], lds[(q * 8 + 3) * 260 + px]);
        w.z = pack2(lds[(q * 8 + 4) * 260 + px], lds[(q * 8 + 5) * 260 + px]);
        w.w = pack2(lds[(q * 8 + 6) * 260 + px], lds[(q * 8 + 7) * 260 + px]);
        *(uint4*)(dst + q * 8) = w;
    }
}

// ---------------------------------------------------------------------------
// hconv (coalesced rewrite): prev_h f32 -> S[n][sy][sx][64+c] bf16.
// Stage 64 channel-rows (130 px each) via coalesced scalar reads into LDS,
// then emit packed NHWC uint4 writes.  grid (130 sy, 4 n).
// ---------------------------------------------------------------------------
__global__ __launch_bounds__(256) void hconv(
    const float* __restrict__ prev_h, unsigned short* __restrict__ S)
{
    __shared__ float lds[64 * 132];   // 33.8 KB
    const int sy = blockIdx.x, n = blockIdx.y, tid = threadIdx.x;
    const float* base = prev_h + ((n * 64) * 320 + (31 + sy)) * 320 + 31;

    for (int e = tid; e < 8192; e += 256) {      // ch = e>>7, px = e&127
        int ch = e >> 7, px = e & 127;
        lds[ch * 132 + px] = base[ch * 102400 + px];
    }
    if (tid < 128) {                             // tail px 128,129
        int ch = tid & 63, px = 128 + (tid >> 6);
        lds[ch * 132 + px] = base[ch * 102400 + px];
    }
    __syncthreads();

    for (int t = tid; t < 260; t += 256) {       // px = t>>1, half = t&1
        int px = t >> 1, half = t & 1;
        unsigned short* dst = S + (((n * 130 + sy) * 130 + px) << 7) + 64 + half * 32;
#pragma unroll
        for (int q = 0; q < 4; ++q) {
            const float* r = &lds[(half * 32 + q * 8) * 132 + px];
            uint4 w;
            w.x = pack2(r[0 * 132], r[1 * 132]);
            w.y = pack2(r[2 * 132], r[3 * 132]);
            w.z = pack2(r[4 * 132], r[5 * 132]);
            w.w = pack2(r[6 * 132], r[7 * 132]);
            *(uint4*)(dst + q * 8) = w;
        }
    }
}

// ---------------------------------------------------------------------------
// conv1 via MFMA: Xp bf16 NHWC -> S[...][ci 0..63] (x_conv, relu, +bc).
// GEMM: M=64 co, K=25x32, N=64 px (8x8 tile).  (control: unchanged)
// ---------------------------------------------------------------------------
__global__ __launch_bounds__(256) void conv1_mfma(
    const unsigned short* __restrict__ Xp,
    const unsigned short* __restrict__ Wp1,
    const float* __restrict__ bc,
    unsigned short* __restrict__ S)
{
    __shared__ __align__(16) unsigned short patch[361 * 40];

    const int tid  = threadIdx.x;
    const int lane = tid & 63;
    const int wv   = tid >> 6;
    const int l15  = lane & 15;
    const int g    = lane >> 4;

    const int tile = blockIdx.x;
    const int ty0  = (tile >> 4) << 3;
    const int tx0  = (tile & 15) << 3;
    const int n    = blockIdx.y;

    for (int u = tid; u < 1444; u += 256) {
        int pos = u >> 2, ch = u & 3;
        int iyl = pos / 19, ixl = pos - iyl * 19;
        const unsigned short* src =
            Xp + (((n * 260) + 2 * ty0 + iyl) * 260 + 2 * tx0 + ixl) * 32 + ch * 8;
        *(bf16x8*)(&patch[pos * 40 + ch * 8]) = *(const bf16x8*)src;
    }
    __syncthreads();

    f32x4 acc[4];
#pragma unroll
    for (int cf = 0; cf < 4; ++cf)
#pragma unroll
        for (int e = 0; e < 4; ++e) acc[cf][e] = 0.f;

    const unsigned short* Abase = Wp1 + (wv * 16 + l15) * 32 + g * 8;
    const int posBase = (2 * (l15 >> 3)) * 19 + 2 * (l15 & 7);
    const unsigned short* Bbase = patch + posBase * 40 + g * 8;

#pragma unroll
    for (int tap = 0; tap < 25; ++tap) {
        const int ky = tap / 5, kx = tap % 5;
        bf16x8 a = *(const bf16x8*)(Abase + tap * 2048);
        const unsigned short* Bt = Bbase + (ky * 19 + kx) * 40;
#pragma unroll
        for (int cf = 0; cf < 4; ++cf) {
            bf16x8 b = *(const bf16x8*)(Bt + cf * (76 * 40));
            acc[cf] = __builtin_amdgcn_mfma_f32_16x16x32_bf16(a, b, acc[cf], 0, 0, 0);
        }
    }

#pragma unroll
    for (int cf = 0; cf < 4; ++cf) {
        int p  = cf * 16 + l15;
        int oh = ty0 + (p >> 3);
        int ow = tx0 + (p & 7);
        int co = wv * 16 + g * 4;
        float v0 = fmaxf(acc[cf][0] + bc[co + 0], 0.f);
        float v1 = fmaxf(acc[cf][1] + bc[co + 1], 0.f);
        float v2 = fmaxf(acc[cf][2] + bc[co + 2], 0.f);
        float v3 = fmaxf(acc[cf][3] + bc[co + 3], 0.f);
        uint2 w;
        w.x = pack2(v0, v1);
        w.y = pack2(v2, v3);
        *(uint2*)(S + (((n * 130 + 1 + oh) * 130 + 1 + ow) << 7) + co) = w;
    }
}

// ---------------------------------------------------------------------------
// gates conv (3x3 over S 130x130x128 NHWC) + fused LSTM epilogue, bf16 MFMA.
// A-loads now fragment-ordered & fully coalesced: WpV[(tap*4+chunk)*1024
// + i*256 + tid].
// ---------------------------------------------------------------------------
__global__ __launch_bounds__(256) void gates_mfma(
    const unsigned short* __restrict__ S,
    const float* __restrict__ prev_c,
    const unsigned short* __restrict__ Wp,      // fragment-ordered
    const float* __restrict__ bg,
    float* __restrict__ out)
{
    __shared__ __align__(16) unsigned short patch[100 * 136];

    const int tid  = threadIdx.x;
    const int lane = tid & 63;
    const int wv   = tid >> 6;
    const int l15  = lane & 15;
    const int g    = lane >> 4;

    const int tile = blockIdx.x;
    const int ty0  = (tile >> 4) << 3;
    const int tx0  = (tile & 15) << 3;
    const int n    = blockIdx.y;

    for (int u = tid; u < 1600; u += 256) {
        int pos = u >> 4, ch = u & 15;
        int y = pos / 10, xx = pos - y * 10;
        const unsigned short* src =
            S + (((n * 130 + ty0 + y) * 130 + tx0 + xx) << 7) + ch * 8;
        *(bf16x8*)(&patch[pos * 136 + ch * 8]) = *(const bf16x8*)src;
    }
    __syncthreads();

    f32x4 acc[4][4];
#pragma unroll
    for (int i = 0; i < 4; ++i)
#pragma unroll
        for (int j = 0; j < 4; ++j)
#pragma unroll
            for (int e = 0; e < 4; ++e) acc[i][j][e] = 0.f;

    const bf16x8* WpV = (const bf16x8*)Wp;
    const int bb = (l15 >> 3) * 10 + (l15 & 7);

    for (int tap = 0; tap < 9; ++tap) {
        const int ky = tap / 3;
        const int kx = tap - ky * 3;
        const int koff = ky * 10 + kx;
        const unsigned short* Bt = patch + (bb + koff) * 136 + g * 8;
#pragma unroll
        for (int chunk = 0; chunk < 4; ++chunk) {
            const bf16x8* Av = WpV + (tap * 4 + chunk) * 1024 + tid;
            bf16x8 a0 = Av[0];
            bf16x8 a1 = Av[256];
            bf16x8 a2 = Av[512];
            bf16x8 a3 = Av[768];
            const unsigned short* pb = Bt + chunk * 32;
            bf16x8 b0 = *(const bf16x8*)(pb + 0 * 2720);
            bf16x8 b1 = *(const bf16x8*)(pb + 1 * 2720);
            bf16x8 b2 = *(const bf16x8*)(pb + 2 * 2720);
            bf16x8 b3 = *(const bf16x8*)(pb + 3 * 2720);
            acc[0][0] = __builtin_amdgcn_mfma_f32_16x16x32_bf16(a0, b0, acc[0][0], 0, 0, 0);
            acc[0][1] = __builtin_amdgcn_mfma_f32_16x16x32_bf16(a0, b1, acc[0][1], 0, 0, 0);
            acc[0][2] = __builtin_amdgcn_mfma_f32_16x16x32_bf16(a0, b2, acc[0][2], 0, 0, 0);
            acc[0][3] = __builtin_amdgcn_mfma_f32_16x16x32_bf16(a0, b3, acc[0][3], 0, 0, 0);
            acc[1][0] = __builtin_amdgcn_mfma_f32_16x16x32_bf16(a1, b0, acc[1][0], 0, 0, 0);
            acc[1][1] = __builtin_amdgcn_mfma_f32_16x16x32_bf16(a1, b1, acc[1][1], 0, 0, 0);
            acc[1][2] = __builtin_amdgcn_mfma_f32_16x16x32_bf16(a1, b2, acc[1][2], 0, 0, 0);
            acc[1][3] = __builtin_amdgcn_mfma_f32_16x16x32_bf16(a1, b3, acc[1][3], 0, 0, 0);
            acc[2][0] = __builtin_amdgcn_mfma_f32_16x16x32_bf16(a2, b0, acc[2][0], 0, 0, 0);
            acc[2][1] = __builtin_amdgcn_mfma_f32_16x16x32_bf16(a2, b1, acc[2][1], 0, 0, 0);
            acc[2][2] = __builtin_amdgcn_mfma_f32_16x16x32_bf16(a2, b2, acc[2][2], 0, 0, 0);
            acc[2][3] = __builtin_amdgcn_mfma_f32_16x16x32_bf16(a2, b3, acc[2][3], 0, 0, 0);
            acc[3][0] = __builtin_amdgcn_mfma_f32_16x16x32_bf16(a3, b0, acc[3][0], 0, 0, 0);
            acc[3][1] = __builtin_amdgcn_mfma_f32_16x16x32_bf16(a3, b1, acc[3][1], 0, 0, 0);
            acc[3][2] = __builtin_amdgcn_mfma_f32_16x16x32_bf16(a3, b2, acc[3][2], 0, 0, 0);
            acc[3][3] = __builtin_amdgcn_mfma_f32_16x16x32_bf16(a3, b3, acc[3][3], 0, 0, 0);
        }
    }

#pragma unroll
    for (int cf = 0; cf < 4; ++cf) {
        int p  = cf * 16 + l15;
        int oh = ty0 + (p >> 3);
        int ow = tx0 + (p & 7);
#pragma unroll
        for (int r = 0; r < 4; ++r) {
            int c = wv * 16 + g * 4 + r;
            float ig = acc[0][cf][r] + bg[c];
            float rg = acc[1][cf][r] + bg[64 + c];
            float og = acc[2][cf][r] + bg[128 + c];
            float gg = acc[3][cf][r] + bg[192 + c];
            float pc = prev_c[((n * 64 + c) * 320 + (32 + oh)) * 320 + (32 + ow)];
            float cell = sigm(rg) * pc + sigm(ig) * tanhf(gg);
            float hid  = sigm(og) * tanhf(cell);
            out[((n * 64 + c) * 128 + oh) * 128 + ow] = hid;
            out[OFF_NEWH + ((n * 64 + c) * 320 + (32 + oh)) * 320 + (32 + ow)] = hid;
            out[OFF_NEWC + ((n * 64 + c) * 320 + (32 + oh)) * 320 + (32 + ow)] = cell;
        }
    }
}

// ---------------------------------------------------------------------------
__global__ __launch_bounds__(256) void copy_f4(
    const float4* __restrict__ src, float4* __restrict__ dst, int n4)
{
    int i = blockIdx.x * blockDim.x + threadIdx.x;
    int stride = gridDim.x * blockDim.x;
    for (; i < n4; i += stride) dst[i] = src[i];
}

extern "C" void kernel_launch(void* const* d_in, const int* in_sizes, int n_in,
                              void* d_out, int out_size, void* d_ws, size_t ws_size,
                              hipStream_t stream)
{
    const float* x      = (const float*)d_in[0];
    const float* prev_h = (const float*)d_in[1];
    const float* prev_c = (const float*)d_in[2];
    const float* Wc     = (const float*)d_in[3];
    const float* bc     = (const float*)d_in[4];
    const float* Wg     = (const float*)d_in[5];
    const float* bg     = (const float*)d_in[6];

    float* out = (float*)d_out;
    unsigned short* S   = (unsigned short*)d_ws;
    unsigned short* Xp  = S + S_ELEMS;
    unsigned short* Wp  = S + WP_OFF;
    unsigned short* Wp1 = S + WP1_OFF;

    hipMemsetAsync(S,  0, (size_t)S_ELEMS * 2, stream);
    hipMemsetAsync(Xp, 0, (size_t)S_ELEMS * 2, stream);

    const int n4 = 26214400 / 4;
    copy_f4<<<2048, 256, 0, stream>>>((const float4*)prev_h, (float4*)(out + OFF_NEWH), n4);
    copy_f4<<<2048, 256, 0, stream>>>((const float4*)prev_c, (float4*)(out + OFF_NEWC), n4);

    pack_wg<<<1152, 256, 0, stream>>>(Wg, Wp);
    pack_wc<<<200, 256, 0, stream>>>(Wc, Wp1);
    xpose_x<<<dim3(256, 4), 256, 0, stream>>>(x, Xp);
    hconv<<<dim3(130, 4), 256, 0, stream>>>(prev_h, S);
    conv1_mfma<<<dim3(256, 4), 256, 0, stream>>>(Xp, Wp1, bc, S);
    gates_mfma<<<dim3(256, 4), 256, 0, stream>>>(S, prev_c, Wp, bg, out);
}